// Round 7
// baseline (36.498 us; speedup 1.0000x reference)
//
#include <hip/hip_runtime.h>
#include <math.h>
#include <float.h>

#define BB 16
#define NN 2382
#define EPSF 1e-5f
#define NV4 9528            // BB*NN/4
#define L2E 1.4426950408889634f
#define TT 64               // G-table nodes per batch
#define MSUB 149            // m's per 16-lane sub-thread (16*149 >= NN)
#define NWAVE 16            // waves per ka block

// ws float layout
#define WS_Y   64           // 38112 pre-BN2 y
#define WS_YS  38912        // 16 per-batch exact sums
#define WS_YQ  38976        // 16 per-batch exact sumsq

// One block per batch: z-stats (redundant), params + power iteration,
// stage K/P/q/r in LDS, 64-node G table, lerp y for all n, exact batch stats.
__global__ __launch_bounds__(1024) void ka_all(
    const float* __restrict__ z,  const float* __restrict__ w1,
    const float* __restrict__ g1, const float* __restrict__ be1,
    const float* __restrict__ wq, const float* __restrict__ bqp,
    const float* __restrict__ wk, const float* __restrict__ bkp,
    const float* __restrict__ wv, const float* __restrict__ bv,
    const float* __restrict__ gammap,
    const float* __restrict__ w2, const float* __restrict__ b2p,
    float* __restrict__ ws)
{
    __shared__ float2 sKP[NN];      // {K[m], P[m]}
    __shared__ float2 sQR[NN];      // {q[n], r[n]}
    __shared__ float  sG[TT];
    __shared__ float  sred[4*NWAVE];
    const int tid  = threadIdx.x;
    const int wave = tid >> 6, lane = tid & 63;
    const int b = blockIdx.x;

    // ---------- z stats (redundant per block; z is L2/L3-resident) ----------
    const float4* __restrict__ z4 = (const float4*)z;
    float s = 0.f, s2 = 0.f;
    for (int i = tid; i < NV4; i += 1024) {
        const float4 v = z4[i];
        s += v.x + v.y + v.z + v.w;
        s2 = fmaf(v.x,v.x, fmaf(v.y,v.y, fmaf(v.z,v.z, fmaf(v.w,v.w, s2))));
    }
    #pragma unroll
    for (int off = 32; off; off >>= 1) {
        s  += __shfl_xor(s, off);
        s2 += __shfl_xor(s2, off);
    }
    if (lane == 0) { sred[wave] = s; sred[NWAVE+wave] = s2; }
    __syncthreads();
    float zs = 0.f, zq = 0.f;
    #pragma unroll
    for (int j = 0; j < NWAVE; ++j) { zs += sred[j]; zq += sred[NWAVE+j]; }
    const float invn = 1.f/(float)(BB*NN);
    const float mz = zs*invn;
    const float vz = zq*invn - mz*mz;
    __syncthreads();   // sred reused

    // ---------- wave-parallel power iteration on M = wv^T wv ----------------
    const int pi = lane >> 3, pj = lane & 7;
    float Mij = 0.f;
    #pragma unroll
    for (int o = 0; o < 8; ++o) Mij = fmaf(wv[o*8+pi], wv[o*8+pj], Mij);
    float u = 1.f, nr = 1.f;
    for (int it = 0; it < 32; ++it) {
        float a = Mij*u;
        a += __shfl_xor(a,1); a += __shfl_xor(a,2); a += __shfl_xor(a,4);
        float bb = a*a;
        bb += __shfl_xor(bb,8); bb += __shfl_xor(bb,16); bb += __shfl_xor(bb,32);
        nr = sqrtf(bb);
        u = __shfl(a, pj<<3) / nr;
    }
    const float invsig = rsqrtf(nr);    // 1/sigma_max(wv)

    // ---------- derived params ----------------------------------------------
    float n1=0.f, nq=0.f, nk=0.f, n2=0.f;
    #pragma unroll
    for (int h=0; h<8; ++h) {
        n1 = fmaf(w1[h], w1[h], n1);
        nq = fmaf(wq[h], wq[h], nq);
        nk = fmaf(wk[h], wk[h], nk);
        n2 = fmaf(w2[h], w2[h], n2);
    }
    n1 = sqrtf(n1); nq = sqrtf(nq); nk = sqrtf(nk); n2 = sqrtf(n2);

    float a1[8], c1[8], wqn[8], wkn[8], w2n[8], wvP[8];
    #pragma unroll
    for (int h=0; h<8; ++h) {
        const float w1n = w1[h]/n1;
        const float rs = rsqrtf(fmaf(w1n*w1n, vz, EPSF));
        a1[h]  = w1n * rs * g1[h];          // x_h = relu(a1*z + c1)
        c1[h]  = be1[h] - mz*a1[h];         // b1 cancels in train-mode BN
        wqn[h] = wq[h]/nq;
        wkn[h] = wk[h]/nk;
        w2n[h] = w2[h]/n2;
    }
    float bvP = 0.f;
    #pragma unroll
    for (int h=0; h<8; ++h) bvP = fmaf(w2n[h], bv[h], bvP);
    #pragma unroll
    for (int c=0; c<8; ++c) {
        float a = 0.f;
        #pragma unroll
        for (int h=0; h<8; ++h) a = fmaf(w2n[h], wv[h*8+c], a);
        wvP[c] = a * invsig;
    }
    const float bq = bqp[0], bk = bkp[0], b2 = b2p[0], gamma = gammap[0];

    // ---------- stage K,P,q,r; k/q ranges ------------------------------------
    const float* __restrict__ zb = z + b*NN;
    float lkmax=-FLT_MAX, lkmin=FLT_MAX, lqmax=-FLT_MAX, lqmin=FLT_MAX;
    for (int m = tid; m < NN; m += 1024) {
        const float zv = zb[m];
        float xh[8];
        #pragma unroll
        for (int h=0;h<8;++h) xh[h] = fmaxf(fmaf(a1[h], zv, c1[h]), 0.f);
        float kk = bk, pp = bvP, qq = bq, rr = b2;
        #pragma unroll
        for (int h=0;h<8;++h) {
            kk = fmaf(wkn[h], xh[h], kk);
            pp = fmaf(wvP[h], xh[h], pp);
            qq = fmaf(wqn[h], xh[h], qq);
            rr = fmaf(w2n[h], xh[h], rr);
        }
        sKP[m] = make_float2(kk, pp);
        sQR[m] = make_float2(qq, rr);
        lkmax = fmaxf(lkmax, kk); lkmin = fminf(lkmin, kk);
        lqmax = fmaxf(lqmax, qq); lqmin = fminf(lqmin, qq);
    }
    #pragma unroll
    for (int off=32; off; off>>=1) {
        lkmax = fmaxf(lkmax, __shfl_xor(lkmax, off));
        lkmin = fminf(lkmin, __shfl_xor(lkmin, off));
        lqmax = fmaxf(lqmax, __shfl_xor(lqmax, off));
        lqmin = fminf(lqmin, __shfl_xor(lqmin, off));
    }
    if (lane == 0) {
        sred[wave]          = lkmax;
        sred[NWAVE+wave]    = lkmin;
        sred[2*NWAVE+wave]  = lqmax;
        sred[3*NWAVE+wave]  = lqmin;
    }
    __syncthreads();
    float kmax=-FLT_MAX, kmin=FLT_MAX, qmax=-FLT_MAX, qmin=FLT_MAX;
    #pragma unroll
    for (int j=0; j<NWAVE; ++j) {
        kmax = fmaxf(kmax, sred[j]);
        kmin = fminf(kmin, sred[NWAVE+j]);
        qmax = fmaxf(qmax, sred[2*NWAVE+j]);
        qmin = fminf(qmin, sred[3*NWAVE+j]);
    }

    // ---------- G table: node = tid>>4, 16 subs over m -----------------------
    const int node = tid >> 4, sub = tid & 15;
    const float xq = fmaf((qmax-qmin), (float)node*(1.f/(float)(TT-1)), qmin);
    const float st = fmaxf(xq*kmax, xq*kmin);     // max_m xq*K[m]
    const float x2 = xq*L2E, st2 = st*L2E;
    float den = 0.f, num = 0.f;
    const int m0 = sub*MSUB;
    const int m1 = (m0+MSUB < NN) ? m0+MSUB : NN;
    for (int m = m0; m < m1; ++m) {
        const float2 kp = sKP[m];
        const float e = __builtin_amdgcn_exp2f(fmaf(x2, kp.x, -st2));
        den += e; num = fmaf(e, kp.y, num);
    }
    #pragma unroll
    for (int off=1; off<16; off<<=1) {
        den += __shfl_xor(den, off);
        num += __shfl_xor(num, off);
    }
    if (sub == 0) sG[node] = num/den;   // den >= 1 (shifted)
    __syncthreads();                     // also separates sred read/reuse

    // ---------- y for all n; exact per-batch stats ---------------------------
    const float qinv = (qmax > qmin) ? (float)(TT-1)/(qmax-qmin) : 0.f;
    float sy = 0.f, sy2 = 0.f;
    for (int n = tid; n < NN; n += 1024) {
        const float2 qr = sQR[n];
        float uu = (qr.x - qmin)*qinv;
        uu = fminf(fmaxf(uu, 0.f), (float)(TT-1));
        int i = (int)uu; if (i > TT-2) i = TT-2;
        const float f = uu - (float)i;
        const float g0 = sG[i], g1v = sG[i+1];
        const float yv = qr.y + gamma*fmaf(f, g1v-g0, g0);
        ws[WS_Y + b*NN + n] = yv;
        sy += yv; sy2 = fmaf(yv, yv, sy2);
    }
    #pragma unroll
    for (int off=32; off; off>>=1) {
        sy  += __shfl_xor(sy,  off);
        sy2 += __shfl_xor(sy2, off);
    }
    if (lane == 0) { sred[wave] = sy; sred[NWAVE+wave] = sy2; }
    __syncthreads();
    if (tid == 0) {
        float ts = 0.f, tq = 0.f;
        #pragma unroll
        for (int j=0; j<NWAVE; ++j) { ts += sred[j]; tq += sred[NWAVE+j]; }
        ws[WS_YS+b] = ts;
        ws[WS_YQ+b] = tq;
    }
}

// 38 blocks: uniform read of 16 exact batch pairs; BN2 + ReLU -> out.
__global__ __launch_bounds__(256) void kb_out(
    const float* __restrict__ ws, const float* __restrict__ g2,
    const float* __restrict__ be2, float* __restrict__ out)
{
    float ts = 0.f, tq = 0.f;
    #pragma unroll
    for (int j=0; j<BB; ++j) { ts += ws[WS_YS+j]; tq += ws[WS_YQ+j]; }
    const float invn = 1.f/(float)(BB*NN);
    const float my = ts*invn;
    const float vy = tq*invn - my*my;
    const float sc = g2[0]*rsqrtf(vy+EPSF);
    const float sh = be2[0] - my*sc;

    const int i = blockIdx.x*256 + threadIdx.x;
    if (i >= NV4) return;
    const float4 v = ((const float4*)(ws + WS_Y))[i];
    float4 o;
    o.x = fmaxf(fmaf(v.x, sc, sh), 0.f);
    o.y = fmaxf(fmaf(v.y, sc, sh), 0.f);
    o.z = fmaxf(fmaf(v.z, sc, sh), 0.f);
    o.w = fmaxf(fmaf(v.w, sc, sh), 0.f);
    ((float4*)out)[i] = o;
}

extern "C" void kernel_launch(void* const* d_in, const int* in_sizes, int n_in,
                              void* d_out, int out_size, void* d_ws, size_t ws_size,
                              hipStream_t stream)
{
    const float* z    = (const float*)d_in[0];
    const float* w1   = (const float*)d_in[1];
    // d_in[2] = b1 (cancels in train-mode BN1)
    const float* g1   = (const float*)d_in[3];
    const float* be1  = (const float*)d_in[4];
    const float* wq   = (const float*)d_in[5];
    const float* bq   = (const float*)d_in[6];
    const float* wk   = (const float*)d_in[7];
    const float* bk   = (const float*)d_in[8];
    const float* wv   = (const float*)d_in[9];
    const float* bv   = (const float*)d_in[10];
    const float* gamma= (const float*)d_in[11];
    const float* w2   = (const float*)d_in[12];
    const float* b2   = (const float*)d_in[13];
    const float* g2   = (const float*)d_in[14];
    const float* be2  = (const float*)d_in[15];
    float* ws  = (float*)d_ws;
    float* out = (float*)d_out;

    ka_all<<<BB, 1024, 0, stream>>>(
        z, w1, g1, be1, wq, bq, wk, bk, wv, bv, gamma, w2, b2, ws);

    kb_out<<<(NV4+255)/256, 256, 0, stream>>>(ws, g2, be2, out);
}